// Round 1
// baseline (502.855 us; speedup 1.0000x reference)
//
#include <hip/hip_runtime.h>
#include <hip/hip_bf16.h>

#define LL 64
#define HH 64
#define BATCH 4096
#define KDIM 4096   // L*H

typedef __attribute__((ext_vector_type(8))) short bf16x8;
typedef __attribute__((ext_vector_type(4))) float f32x4;

__device__ inline short f2bf(float f) {
    __hip_bfloat16 h = __float2bfloat16(f);
    return *reinterpret_cast<short*>(&h);
}
__device__ inline float elu1(float x) { return x > 0.f ? x : expm1f(x); }

__device__ inline void global_load_lds16(const short* g, short* l) {
    __builtin_amdgcn_global_load_lds(
        (const __attribute__((address_space(1))) unsigned int*)g,
        (__attribute__((address_space(3))) unsigned int*)l,
        16, 0, 0);
}

// ---------- transpose + fp32->bf16: in (R,C) f32 -> out (C,R) bf16 ----------
__global__ __launch_bounds__(256) void k_transpose_cvt(
    const float* __restrict__ in, short* __restrict__ out, int R, int C)
{
    __shared__ float tile[32][33];
    int tx = threadIdx.x & 31, ty = threadIdx.x >> 5;   // ty: 0..7
    size_t r0 = (size_t)blockIdx.y * 32, c0 = (size_t)blockIdx.x * 32;
#pragma unroll
    for (int i = 0; i < 32; i += 8)
        tile[ty + i][tx] = in[(r0 + ty + i) * C + (c0 + tx)];
    __syncthreads();
#pragma unroll
    for (int i = 0; i < 32; i += 8)
        out[(c0 + ty + i) * R + (r0 + tx)] = f2bf(tile[tx][ty + i]);
}

// ---------- layer 1: exact fp32 gather-sum + elu -> A1 bf16 (B, 4096) ----------
__global__ __launch_bounds__(256) void k_layer1(
    const int* __restrict__ x, const float* __restrict__ W0,
    const float* __restrict__ b0, short* __restrict__ A1)
{
    int b = blockIdx.x;
    int tid = threadIdx.x;
    float acc[16];
#pragma unroll
    for (int k = 0; k < 16; ++k) acc[k] = b0[tid + k * 256];
    const int* xb = x + b * LL;
    for (int t = 1; t < LL; ++t) {
        int v = xb[t - 1];
        const float* w = W0 + (size_t)(t * 4 + v) * KDIM;
        int fmin = t * HH;
#pragma unroll
        for (int k = 0; k < 16; ++k) {           // static indices: keep acc in regs
            int f = tid + k * 256;
            if (f >= fmin) acc[k] += w[f];
        }
    }
    short* out = A1 + (size_t)b * KDIM;
#pragma unroll
    for (int k = 0; k < 16; ++k) out[tid + k * 256] = f2bf(elu1(acc[k]));
}

// ---------- bf16 MFMA GEMM: C = elu(A(M,K) * BT(N,K)^T + bias), triangular K ----------
// k_end for an n-tile ending at ne: min(K, ne << SHIFT)
template<int SHIFT, bool OUT_BF16>
__global__ __launch_bounds__(256) void k_gemm_bt(
    const short* __restrict__ A,    // (M,K) bf16
    const short* __restrict__ BT,   // (N,K) bf16  (transposed weights)
    const float* __restrict__ bias, // (N)
    void* __restrict__ Cv,          // (M,N) bf16 or f32
    int M, int N, int K)
{
    constexpr int BM = 128, BN = 128, BK = 32;
    __shared__ short As[BM * BK];
    __shared__ short Bs[BN * BK];

    int m0 = blockIdx.x * BM, n0 = blockIdx.y * BN;
    int tid = threadIdx.x;
    int wave = tid >> 6, lane = tid & 63;
    int wm = (wave >> 1) * 64, wn = (wave & 1) * 64;

    int k_end = min(K, (n0 + BN) << SHIFT);

    f32x4 acc[4][4] = {};

    int rsub = lane >> 2;          // 0..15: row within 16-row wave chunk
    int csub = (lane & 3) * 8;     // element offset within 32-elem row
    const short* ga = A  + (size_t)(m0 + wave * 16 + rsub) * K + csub;
    const short* gb = BT + (size_t)(n0 + wave * 16 + rsub) * K + csub;
    short* lA = &As[(wave * 16) * BK];
    short* lB = &Bs[(wave * 16) * BK];

    int lrow = lane & 15;
    int lko  = (lane >> 4) * 8;
    const short* rA = &As[(wm + lrow) * BK + lko];
    const short* rB = &Bs[(wn + lrow) * BK + lko];

    for (int kb = 0; kb < k_end; kb += BK) {
        __syncthreads();
        global_load_lds16(ga + kb,                  lA);
        global_load_lds16(ga + kb + (size_t)64 * K, lA + 64 * BK);
        global_load_lds16(gb + kb,                  lB);
        global_load_lds16(gb + kb + (size_t)64 * K, lB + 64 * BK);
        __syncthreads();

        bf16x8 af[4], bf[4];
#pragma unroll
        for (int i = 0; i < 4; ++i) {
            af[i] = *(const bf16x8*)(rA + i * 16 * BK);
            bf[i] = *(const bf16x8*)(rB + i * 16 * BK);
        }
#pragma unroll
        for (int mi = 0; mi < 4; ++mi)
#pragma unroll
            for (int ni = 0; ni < 4; ++ni)
                acc[mi][ni] = __builtin_amdgcn_mfma_f32_16x16x32_bf16(
                    af[mi], bf[ni], acc[mi][ni], 0, 0, 0);
    }

    int lcol = lane & 15;
    int lr4  = (lane >> 4) * 4;
#pragma unroll
    for (int mi = 0; mi < 4; ++mi) {
#pragma unroll
        for (int ni = 0; ni < 4; ++ni) {
            int col = n0 + wn + ni * 16 + lcol;
            float bv = bias[col];
#pragma unroll
            for (int r = 0; r < 4; ++r) {
                int row = m0 + wm + mi * 16 + lr4 + r;
                float v = elu1(acc[mi][ni][r] + bv);
                if (OUT_BF16) ((short*)Cv)[(size_t)row * N + col] = f2bf(v);
                else          ((float*)Cv)[(size_t)row * N + col] = v;
            }
        }
    }
}

// ---------- logp: per (b,j): out[b,j,x] - logsumexp; wave-reduce over j ----------
__global__ __launch_bounds__(256) void k_logp(
    const float* __restrict__ out, const int* __restrict__ x,
    float* __restrict__ logp)
{
    int b = blockIdx.x * 4 + (threadIdx.x >> 6);
    int j = threadIdx.x & 63;
    f32x4 o = *(const f32x4*)(out + (size_t)b * 256 + j * 4);
    float m = fmaxf(fmaxf(o[0], o[1]), fmaxf(o[2], o[3]));
    float lse = m + logf(expf(o[0] - m) + expf(o[1] - m) +
                         expf(o[2] - m) + expf(o[3] - m));
    int xi = x[b * LL + j];
    float sel = (xi == 0) ? o[0] : (xi == 1) ? o[1] : (xi == 2) ? o[2] : o[3];
    float c = sel - lse;
#pragma unroll
    for (int off = 32; off > 0; off >>= 1)
        c += __shfl_down(c, off, 64);
    if (j == 0) logp[b] = c;
}

extern "C" void kernel_launch(void* const* d_in, const int* in_sizes, int n_in,
                              void* d_out, int out_size, void* d_ws, size_t ws_size,
                              hipStream_t stream)
{
    const int*   x  = (const int*)  d_in[0];
    const float* W0 = (const float*)d_in[1];
    const float* W1 = (const float*)d_in[2];
    const float* W2 = (const float*)d_in[3];
    const float* b0 = (const float*)d_in[4];
    const float* b1 = (const float*)d_in[5];
    const float* b2 = (const float*)d_in[6];
    float* logp = (float*)d_out;

    char* ws = (char*)d_ws;
    short* W1T = (short*)(ws);                         // 4096x4096 bf16 = 32 MiB
    short* W2T = (short*)(ws + (size_t)33554432);      //  256x4096 bf16 =  2 MiB
    short* A1  = (short*)(ws + (size_t)35651584);      // 4096x4096 bf16 = 32 MiB
    short* A2  = (short*)(ws + (size_t)69206016);      // 4096x4096 bf16 = 32 MiB
    float* OUT = (float*)(ws + (size_t)102760448);     // 4096x256  f32  =  4 MiB

    // prep: W1 (K,N)->(N,K) bf16 ; W2 (K,256)->(256,K) bf16
    k_transpose_cvt<<<dim3(128, 128), 256, 0, stream>>>(W1, W1T, 4096, 4096);
    k_transpose_cvt<<<dim3(8, 128), 256, 0, stream>>>(W2, W2T, 4096, 256);

    // layer 1: exact fp32 gather + elu -> A1 (bf16)
    k_layer1<<<4096, 256, 0, stream>>>(x, W0, b0, A1);

    // layer 2: A2 = elu(A1 @ W1flat + b1)   [M=4096,N=4096,K triangular]
    k_gemm_bt<0, true><<<dim3(32, 32), 256, 0, stream>>>(A1, W1T, b1, A2, 4096, 4096, 4096);

    // layer 3: OUT = elu(A2 @ W2flat + b2)  [M=4096,N=256,K triangular]
    k_gemm_bt<4, false><<<dim3(32, 2), 256, 0, stream>>>(A2, W2T, b2, OUT, 4096, 256, 4096);

    // logp
    k_logp<<<1024, 256, 0, stream>>>(OUT, x, logp);
}

// Round 2
// 217.633 us; speedup vs baseline: 2.3106x; 2.3106x over previous
//
#include <hip/hip_runtime.h>
#include <hip/hip_bf16.h>

#define LL 64
#define HH 64
#define KDIM 4096   // L*H

typedef __attribute__((ext_vector_type(8))) short bf16x8;
typedef __attribute__((ext_vector_type(4))) short s16x4;
typedef __attribute__((ext_vector_type(4))) float f32x4;

__device__ inline short f2bf(float f) {
    __hip_bfloat16 h = __float2bfloat16(f);
    return *reinterpret_cast<short*>(&h);
}
__device__ inline float elu1(float x) { return x > 0.f ? x : expm1f(x); }

__device__ inline void global_load_lds16(const short* g, short* l) {
    __builtin_amdgcn_global_load_lds(
        (const __attribute__((address_space(1))) unsigned int*)g,
        (__attribute__((address_space(3))) unsigned int*)l,
        16, 0, 0);
}

// ---------- transpose + fp32->bf16: in (R,C) f32 -> out (C,R) bf16 ----------
__global__ __launch_bounds__(256) void k_transpose_cvt(
    const float* __restrict__ in, short* __restrict__ out, int R, int C)
{
    __shared__ float tile[32][33];
    int tx = threadIdx.x & 31, ty = threadIdx.x >> 5;   // ty: 0..7
    size_t r0 = (size_t)blockIdx.y * 32, c0 = (size_t)blockIdx.x * 32;
#pragma unroll
    for (int i = 0; i < 32; i += 8)
        tile[ty + i][tx] = in[(r0 + ty + i) * C + (c0 + tx)];
    __syncthreads();
#pragma unroll
    for (int i = 0; i < 32; i += 8)
        out[(c0 + ty + i) * R + (r0 + tx)] = f2bf(tile[tx][ty + i]);
}

// ---------- one-hot of shifted x: Xoh (B, 256) bf16 ----------
__global__ __launch_bounds__(256) void k_onehot(
    const int* __restrict__ x, short* __restrict__ Xoh)
{
    int b = blockIdx.x * 4 + (threadIdx.x >> 6);
    int t = threadIdx.x & 63;
    s16x4 v = {0, 0, 0, 0};
    if (t > 0) {
        int xi = x[b * LL + t - 1];
        v[xi] = (short)0x3F80;                    // bf16 1.0
    }
    *(s16x4*)(Xoh + (size_t)b * 256 + t * 4) = v;
}

// ---------- bf16 MFMA GEMM: C = elu(A(M,K) * BT(N,K)^T + bias), triangular K ----------
// SHIFT>=0: k_end=(n0+BN)<<SHIFT ; SHIFT<0: k_end=(n0+BN)>>(-SHIFT) (rounded up to BK by loop)
template<int SHIFT, bool OUT_BF16>
__global__ __launch_bounds__(256) void k_gemm_bt(
    const short* __restrict__ A,    // (M,K) bf16
    const short* __restrict__ BT,   // (N,K) bf16
    const float* __restrict__ bias, // (N)
    void* __restrict__ Cv,          // (M,N) bf16 or f32
    int M, int N, int K)
{
    constexpr int BM = 128, BN = 128, BK = 32;
    __shared__ short As[BM * BK];
    __shared__ short Bs[BN * BK];

    int m0 = blockIdx.x * BM, n0 = blockIdx.y * BN;
    int tid = threadIdx.x;
    int wave = tid >> 6, lane = tid & 63;
    int wm = (wave >> 1) * 64, wn = (wave & 1) * 64;

    int ke;
    if constexpr (SHIFT >= 0) ke = (n0 + BN) << SHIFT;
    else                      ke = (n0 + BN) >> (-SHIFT);
    int k_end = min(K, ke);

    f32x4 acc[4][4] = {};

    int rsub = lane >> 2;
    int csub = (lane & 3) * 8;
    const short* ga = A  + (size_t)(m0 + wave * 16 + rsub) * K + csub;
    const short* gb = BT + (size_t)(n0 + wave * 16 + rsub) * K + csub;
    short* lA = &As[(wave * 16) * BK];
    short* lB = &Bs[(wave * 16) * BK];

    int lrow = lane & 15;
    int lko  = (lane >> 4) * 8;
    const short* rA = &As[(wm + lrow) * BK + lko];
    const short* rB = &Bs[(wn + lrow) * BK + lko];

    for (int kb = 0; kb < k_end; kb += BK) {
        __syncthreads();
        global_load_lds16(ga + kb,                  lA);
        global_load_lds16(ga + kb + (size_t)64 * K, lA + 64 * BK);
        global_load_lds16(gb + kb,                  lB);
        global_load_lds16(gb + kb + (size_t)64 * K, lB + 64 * BK);
        __syncthreads();

        bf16x8 af[4], bf[4];
#pragma unroll
        for (int i = 0; i < 4; ++i) {
            af[i] = *(const bf16x8*)(rA + i * 16 * BK);
            bf[i] = *(const bf16x8*)(rB + i * 16 * BK);
        }
#pragma unroll
        for (int mi = 0; mi < 4; ++mi)
#pragma unroll
            for (int ni = 0; ni < 4; ++ni)
                acc[mi][ni] = __builtin_amdgcn_mfma_f32_16x16x32_bf16(
                    af[mi], bf[ni], acc[mi][ni], 0, 0, 0);
    }

    int lcol = lane & 15;
    int lr4  = (lane >> 4) * 4;
#pragma unroll
    for (int mi = 0; mi < 4; ++mi) {
#pragma unroll
        for (int ni = 0; ni < 4; ++ni) {
            int col = n0 + wn + ni * 16 + lcol;
            float bv = bias[col];
#pragma unroll
            for (int r = 0; r < 4; ++r) {
                int row = m0 + wm + mi * 16 + lr4 + r;
                float v = elu1(acc[mi][ni][r] + bv);
                if (OUT_BF16) ((short*)Cv)[(size_t)row * N + col] = f2bf(v);
                else          ((float*)Cv)[(size_t)row * N + col] = v;
            }
        }
    }
}

// ---------- split-K GEMM partials (layer 3): part[z] = A*BT^T chunk, f32, no epilogue ----------
template<int SHIFT, int ZSPLIT>
__global__ __launch_bounds__(256) void k_gemm_bt_splitk(
    const short* __restrict__ A, const short* __restrict__ BT,
    float* __restrict__ part, int M, int N, int K)
{
    constexpr int BM = 128, BN = 128, BK = 32;
    __shared__ short As[BM * BK];
    __shared__ short Bs[BN * BK];

    int m0 = blockIdx.x * BM, n0 = blockIdx.y * BN;
    int z = blockIdx.z;
    int tid = threadIdx.x;
    int wave = tid >> 6, lane = tid & 63;
    int wm = (wave >> 1) * 64, wn = (wave & 1) * 64;

    int k_end = min(K, (n0 + BN) << SHIFT);
    int chunk = ((k_end / ZSPLIT + BK - 1) / BK) * BK;
    int kb0 = z * chunk;
    int kb1 = min(k_end, kb0 + chunk);

    f32x4 acc[4][4] = {};

    int rsub = lane >> 2;
    int csub = (lane & 3) * 8;
    const short* ga = A  + (size_t)(m0 + wave * 16 + rsub) * K + csub;
    const short* gb = BT + (size_t)(n0 + wave * 16 + rsub) * K + csub;
    short* lA = &As[(wave * 16) * BK];
    short* lB = &Bs[(wave * 16) * BK];

    int lrow = lane & 15;
    int lko  = (lane >> 4) * 8;
    const short* rA = &As[(wm + lrow) * BK + lko];
    const short* rB = &Bs[(wn + lrow) * BK + lko];

    for (int kb = kb0; kb < kb1; kb += BK) {
        __syncthreads();
        global_load_lds16(ga + kb,                  lA);
        global_load_lds16(ga + kb + (size_t)64 * K, lA + 64 * BK);
        global_load_lds16(gb + kb,                  lB);
        global_load_lds16(gb + kb + (size_t)64 * K, lB + 64 * BK);
        __syncthreads();

        bf16x8 af[4], bf[4];
#pragma unroll
        for (int i = 0; i < 4; ++i) {
            af[i] = *(const bf16x8*)(rA + i * 16 * BK);
            bf[i] = *(const bf16x8*)(rB + i * 16 * BK);
        }
#pragma unroll
        for (int mi = 0; mi < 4; ++mi)
#pragma unroll
            for (int ni = 0; ni < 4; ++ni)
                acc[mi][ni] = __builtin_amdgcn_mfma_f32_16x16x32_bf16(
                    af[mi], bf[ni], acc[mi][ni], 0, 0, 0);
    }

    float* p = part + (size_t)z * M * N;
    int lcol = lane & 15;
    int lr4  = (lane >> 4) * 4;
#pragma unroll
    for (int mi = 0; mi < 4; ++mi)
#pragma unroll
        for (int ni = 0; ni < 4; ++ni) {
            int col = n0 + wn + ni * 16 + lcol;
#pragma unroll
            for (int r = 0; r < 4; ++r) {
                int row = m0 + wm + mi * 16 + lr4 + r;
                p[(size_t)row * N + col] = acc[mi][ni][r];
            }
        }
}

// ---------- layer-3 reduce: OUT = elu(sum_z part[z] + b2) ----------
__global__ __launch_bounds__(256) void k_l3_reduce(
    const float* __restrict__ part, const float* __restrict__ b2,
    float* __restrict__ OUT)
{
    const size_t MN = (size_t)4096 * 256;
    size_t idx = (size_t)blockIdx.x * 256 + threadIdx.x;
    int col = idx & 255;
    float v = part[idx] + part[idx + MN] + part[idx + 2 * MN] + part[idx + 3 * MN]
            + b2[col];
    OUT[idx] = elu1(v);
}

// ---------- logp ----------
__global__ __launch_bounds__(256) void k_logp(
    const float* __restrict__ out, const int* __restrict__ x,
    float* __restrict__ logp)
{
    int b = blockIdx.x * 4 + (threadIdx.x >> 6);
    int j = threadIdx.x & 63;
    f32x4 o = *(const f32x4*)(out + (size_t)b * 256 + j * 4);
    float m = fmaxf(fmaxf(o[0], o[1]), fmaxf(o[2], o[3]));
    float lse = m + logf(expf(o[0] - m) + expf(o[1] - m) +
                         expf(o[2] - m) + expf(o[3] - m));
    int xi = x[b * LL + j];
    float sel = (xi == 0) ? o[0] : (xi == 1) ? o[1] : (xi == 2) ? o[2] : o[3];
    float c = sel - lse;
#pragma unroll
    for (int off = 32; off > 0; off >>= 1)
        c += __shfl_down(c, off, 64);
    if (j == 0) logp[b] = c;
}

extern "C" void kernel_launch(void* const* d_in, const int* in_sizes, int n_in,
                              void* d_out, int out_size, void* d_ws, size_t ws_size,
                              hipStream_t stream)
{
    const int*   x  = (const int*)  d_in[0];
    const float* W0 = (const float*)d_in[1];
    const float* W1 = (const float*)d_in[2];
    const float* W2 = (const float*)d_in[3];
    const float* b0 = (const float*)d_in[4];
    const float* b1 = (const float*)d_in[5];
    const float* b2 = (const float*)d_in[6];
    float* logp = (float*)d_out;

    char* ws = (char*)d_ws;
    short* W1T  = (short*)(ws);                        // 4096x4096 bf16 = 32 MiB
    short* W2T  = (short*)(ws + (size_t)33554432);     //  256x4096 bf16 =  2 MiB
    short* W0T  = (short*)(ws + (size_t)35651584);     // 4096x256  bf16 =  2 MiB
    short* Xoh  = (short*)(ws + (size_t)37748736);     // 4096x256  bf16 =  2 MiB
    short* A1   = (short*)(ws + (size_t)39845888);     // 4096x4096 bf16 = 32 MiB
    float* part = (float*)(ws + (size_t)39845888);     // aliases A1 (dead by layer 3): 16 MiB
    short* A2   = (short*)(ws + (size_t)73400320);     // 4096x4096 bf16 = 32 MiB
    float* OUT  = (float*)(ws + (size_t)106954752);    // 4096x256  f32  =  4 MiB

    // weight prep
    k_transpose_cvt<<<dim3(128, 128), 256, 0, stream>>>(W1, W1T, 4096, 4096);
    k_transpose_cvt<<<dim3(8, 128),   256, 0, stream>>>(W2, W2T, 4096, 256);
    k_transpose_cvt<<<dim3(128, 8),   256, 0, stream>>>(W0, W0T, 256, 4096);

    // one-hot of shifted x
    k_onehot<<<1024, 256, 0, stream>>>(x, Xoh);

    // layer 1: A1 = elu(Xoh @ W0flat + b0)   [M=4096,N=4096,K=256, k_end=(n0+BN)>>4]
    k_gemm_bt<-4, true><<<dim3(32, 32), 256, 0, stream>>>(Xoh, W0T, b0, A1, 4096, 4096, 256);

    // layer 2: A2 = elu(A1 @ W1flat + b1)    [M=4096,N=4096,K triangular]
    k_gemm_bt<0, true><<<dim3(32, 32), 256, 0, stream>>>(A1, W1T, b1, A2, 4096, 4096, 4096);

    // layer 3: split-K partials + reduce     [M=4096,N=256]
    k_gemm_bt_splitk<4, 4><<<dim3(32, 2, 4), 256, 0, stream>>>(A2, W2T, part, 4096, 256, 4096);
    k_l3_reduce<<<4096, 256, 0, stream>>>(part, b2, OUT);

    // logp
    k_logp<<<1024, 256, 0, stream>>>(OUT, x, logp);
}

// Round 3
// 182.667 us; speedup vs baseline: 2.7529x; 1.1914x over previous
//
#include <hip/hip_runtime.h>
#include <hip/hip_bf16.h>

#define LL 64
#define HH 64
#define KDIM 4096   // L*H

typedef __attribute__((ext_vector_type(8))) short bf16x8;
typedef __attribute__((ext_vector_type(4))) short s16x4;
typedef __attribute__((ext_vector_type(4))) float f32x4;

__device__ inline short f2bf(float f) {
    __hip_bfloat16 h = __float2bfloat16(f);
    return *reinterpret_cast<short*>(&h);
}
__device__ inline float elu1(float x) { return x > 0.f ? x : expm1f(x); }

__device__ inline void global_load_lds16(const short* g, short* l) {
    __builtin_amdgcn_global_load_lds(
        (const __attribute__((address_space(1))) unsigned int*)g,
        (__attribute__((address_space(3))) unsigned int*)l,
        16, 0, 0);
}

// ---------- transpose + fp32->bf16: in (R,C) f32 -> out (C,R) bf16 ----------
// skip_margin >= 0: skip tiles with r0 >= c0 + skip_margin (block-triangular input,
// and consumer never reads k > n+127 -> margin 160 is safe for W1).
__global__ __launch_bounds__(256) void k_transpose_cvt(
    const float* __restrict__ in, short* __restrict__ out, int R, int C,
    int skip_margin)
{
    __shared__ float tile[32][33];
    int tx = threadIdx.x & 31, ty = threadIdx.x >> 5;   // ty: 0..7
    size_t r0 = (size_t)blockIdx.y * 32, c0 = (size_t)blockIdx.x * 32;
    if (skip_margin >= 0 && (int)r0 >= (int)c0 + skip_margin) return;
#pragma unroll
    for (int i = 0; i < 32; i += 8)
        tile[ty + i][tx] = in[(r0 + ty + i) * C + (c0 + tx)];
    __syncthreads();
#pragma unroll
    for (int i = 0; i < 32; i += 8)
        out[(c0 + ty + i) * R + (r0 + tx)] = f2bf(tile[tx][ty + i]);
}

// ---------- one-hot of shifted x: Xoh (B, 256) bf16 ----------
__global__ __launch_bounds__(256) void k_onehot(
    const int* __restrict__ x, short* __restrict__ Xoh)
{
    int b = blockIdx.x * 4 + (threadIdx.x >> 6);
    int t = threadIdx.x & 63;
    s16x4 v = {0, 0, 0, 0};
    if (t > 0) {
        int xi = x[b * LL + t - 1];
        v[xi] = (short)0x3F80;                    // bf16 1.0
    }
    *(s16x4*)(Xoh + (size_t)b * 256 + t * 4) = v;
}

// ---------- bf16 MFMA GEMM: C = elu(A(M,K) * BT(N,K)^T + bias), triangular K ----------
// n-tiles dispatched heaviest-first (reversed y) for triangular load balance.
// SHIFT>=0: k_end=(n0+BN)<<SHIFT ; SHIFT<0: k_end=(n0+BN)>>(-SHIFT)
template<int SHIFT, bool OUT_BF16>
__global__ __launch_bounds__(256) void k_gemm_bt(
    const short* __restrict__ A,    // (M,K) bf16
    const short* __restrict__ BT,   // (N,K) bf16
    const float* __restrict__ bias, // (N)
    void* __restrict__ Cv,          // (M,N) bf16 or f32
    int M, int N, int K)
{
    constexpr int BM = 128, BN = 128, BK = 32;
    __shared__ short As[BM * BK];
    __shared__ short Bs[BN * BK];

    int m0 = blockIdx.x * BM;
    int n0 = ((int)gridDim.y - 1 - (int)blockIdx.y) * BN;   // heaviest-first
    int tid = threadIdx.x;
    int wave = tid >> 6, lane = tid & 63;
    int wm = (wave >> 1) * 64, wn = (wave & 1) * 64;

    int ke;
    if constexpr (SHIFT >= 0) ke = (n0 + BN) << SHIFT;
    else                      ke = (n0 + BN) >> (-SHIFT);
    int k_end = min(K, ke);

    f32x4 acc[4][4] = {};

    int rsub = lane >> 2;
    int csub = (lane & 3) * 8;
    const short* ga = A  + (size_t)(m0 + wave * 16 + rsub) * K + csub;
    const short* gb = BT + (size_t)(n0 + wave * 16 + rsub) * K + csub;
    short* lA = &As[(wave * 16) * BK];
    short* lB = &Bs[(wave * 16) * BK];

    int lrow = lane & 15;
    int lko  = (lane >> 4) * 8;
    const short* rA = &As[(wm + lrow) * BK + lko];
    const short* rB = &Bs[(wn + lrow) * BK + lko];

    for (int kb = 0; kb < k_end; kb += BK) {
        __syncthreads();
        global_load_lds16(ga + kb,                  lA);
        global_load_lds16(ga + kb + (size_t)64 * K, lA + 64 * BK);
        global_load_lds16(gb + kb,                  lB);
        global_load_lds16(gb + kb + (size_t)64 * K, lB + 64 * BK);
        __syncthreads();

        bf16x8 af[4], bf[4];
#pragma unroll
        for (int i = 0; i < 4; ++i) {
            af[i] = *(const bf16x8*)(rA + i * 16 * BK);
            bf[i] = *(const bf16x8*)(rB + i * 16 * BK);
        }
#pragma unroll
        for (int mi = 0; mi < 4; ++mi)
#pragma unroll
            for (int ni = 0; ni < 4; ++ni)
                acc[mi][ni] = __builtin_amdgcn_mfma_f32_16x16x32_bf16(
                    af[mi], bf[ni], acc[mi][ni], 0, 0, 0);
    }

    int lcol = lane & 15;
    int lr4  = (lane >> 4) * 4;
#pragma unroll
    for (int mi = 0; mi < 4; ++mi) {
#pragma unroll
        for (int ni = 0; ni < 4; ++ni) {
            int col = n0 + wn + ni * 16 + lcol;
            float bv = bias[col];
#pragma unroll
            for (int r = 0; r < 4; ++r) {
                int row = m0 + wm + mi * 16 + lr4 + r;
                float v = elu1(acc[mi][ni][r] + bv);
                if (OUT_BF16) ((short*)Cv)[(size_t)row * N + col] = f2bf(v);
                else          ((float*)Cv)[(size_t)row * N + col] = v;
            }
        }
    }
}

// ---------- split-K GEMM partials (layer 3): part[z] = A*BT^T chunk, f32 ----------
template<int SHIFT, int ZSPLIT>
__global__ __launch_bounds__(256) void k_gemm_bt_splitk(
    const short* __restrict__ A, const short* __restrict__ BT,
    float* __restrict__ part, int M, int N, int K)
{
    constexpr int BM = 128, BN = 128, BK = 32;
    __shared__ short As[BM * BK];
    __shared__ short Bs[BN * BK];

    int m0 = blockIdx.x * BM;
    int n0 = ((int)gridDim.y - 1 - (int)blockIdx.y) * BN;   // heaviest-first
    int z = blockIdx.z;
    int tid = threadIdx.x;
    int wave = tid >> 6, lane = tid & 63;
    int wm = (wave >> 1) * 64, wn = (wave & 1) * 64;

    int k_end = min(K, (n0 + BN) << SHIFT);
    int chunk = ((k_end / ZSPLIT + BK - 1) / BK) * BK;
    int kb0 = z * chunk;
    int kb1 = min(k_end, kb0 + chunk);

    f32x4 acc[4][4] = {};

    int rsub = lane >> 2;
    int csub = (lane & 3) * 8;
    const short* ga = A  + (size_t)(m0 + wave * 16 + rsub) * K + csub;
    const short* gb = BT + (size_t)(n0 + wave * 16 + rsub) * K + csub;
    short* lA = &As[(wave * 16) * BK];
    short* lB = &Bs[(wave * 16) * BK];

    int lrow = lane & 15;
    int lko  = (lane >> 4) * 8;
    const short* rA = &As[(wm + lrow) * BK + lko];
    const short* rB = &Bs[(wn + lrow) * BK + lko];

    for (int kb = kb0; kb < kb1; kb += BK) {
        __syncthreads();
        global_load_lds16(ga + kb,                  lA);
        global_load_lds16(ga + kb + (size_t)64 * K, lA + 64 * BK);
        global_load_lds16(gb + kb,                  lB);
        global_load_lds16(gb + kb + (size_t)64 * K, lB + 64 * BK);
        __syncthreads();

        bf16x8 af[4], bf[4];
#pragma unroll
        for (int i = 0; i < 4; ++i) {
            af[i] = *(const bf16x8*)(rA + i * 16 * BK);
            bf[i] = *(const bf16x8*)(rB + i * 16 * BK);
        }
#pragma unroll
        for (int mi = 0; mi < 4; ++mi)
#pragma unroll
            for (int ni = 0; ni < 4; ++ni)
                acc[mi][ni] = __builtin_amdgcn_mfma_f32_16x16x32_bf16(
                    af[mi], bf[ni], acc[mi][ni], 0, 0, 0);
    }

    float* p = part + (size_t)z * M * N;
    int lcol = lane & 15;
    int lr4  = (lane >> 4) * 4;
#pragma unroll
    for (int mi = 0; mi < 4; ++mi)
#pragma unroll
        for (int ni = 0; ni < 4; ++ni) {
            int col = n0 + wn + ni * 16 + lcol;
#pragma unroll
            for (int r = 0; r < 4; ++r) {
                int row = m0 + wm + mi * 16 + lr4 + r;
                p[(size_t)row * N + col] = acc[mi][ni][r];
            }
        }
}

// ---------- fused: reduce split-K partials + bias + elu + log-softmax + gather ----------
__global__ __launch_bounds__(256) void k_logp_fused(
    const float* __restrict__ part, const float* __restrict__ b2,
    const int* __restrict__ x, float* __restrict__ logp)
{
    const size_t MN = (size_t)4096 * 256;
    int b = blockIdx.x * 4 + (threadIdx.x >> 6);
    int j = threadIdx.x & 63;
    size_t idx = (size_t)b * 256 + j * 4;

    f32x4 o = *(const f32x4*)(part + idx);
    f32x4 p1 = *(const f32x4*)(part + idx + MN);
    f32x4 p2 = *(const f32x4*)(part + idx + 2 * MN);
    f32x4 p3 = *(const f32x4*)(part + idx + 3 * MN);
    f32x4 bv = *(const f32x4*)(b2 + j * 4);
#pragma unroll
    for (int s = 0; s < 4; ++s)
        o[s] = elu1(o[s] + p1[s] + p2[s] + p3[s] + bv[s]);

    float m = fmaxf(fmaxf(o[0], o[1]), fmaxf(o[2], o[3]));
    float lse = m + logf(expf(o[0] - m) + expf(o[1] - m) +
                         expf(o[2] - m) + expf(o[3] - m));
    int xi = x[b * LL + j];
    float sel = (xi == 0) ? o[0] : (xi == 1) ? o[1] : (xi == 2) ? o[2] : o[3];
    float c = sel - lse;
#pragma unroll
    for (int off = 32; off > 0; off >>= 1)
        c += __shfl_down(c, off, 64);
    if (j == 0) logp[b] = c;
}

extern "C" void kernel_launch(void* const* d_in, const int* in_sizes, int n_in,
                              void* d_out, int out_size, void* d_ws, size_t ws_size,
                              hipStream_t stream)
{
    const int*   x  = (const int*)  d_in[0];
    const float* W0 = (const float*)d_in[1];
    const float* W1 = (const float*)d_in[2];
    const float* W2 = (const float*)d_in[3];
    const float* b0 = (const float*)d_in[4];
    const float* b1 = (const float*)d_in[5];
    const float* b2 = (const float*)d_in[6];
    float* logp = (float*)d_out;

    char* ws = (char*)d_ws;
    short* W1T  = (short*)(ws);                        // 4096x4096 bf16 = 32 MiB
    short* W2T  = (short*)(ws + (size_t)33554432);     //  256x4096 bf16 =  2 MiB
    short* W0T  = (short*)(ws + (size_t)35651584);     // 4096x256  bf16 =  2 MiB
    short* Xoh  = (short*)(ws + (size_t)37748736);     // 4096x256  bf16 =  2 MiB
    short* A1   = (short*)(ws + (size_t)39845888);     // 4096x4096 bf16 = 32 MiB
    float* part = (float*)(ws + (size_t)39845888);     // aliases A1 (dead by layer 3): 16 MiB
    short* A2   = (short*)(ws + (size_t)73400320);     // 4096x4096 bf16 = 32 MiB

    // weight prep (W1: skip transpose tiles with r0 >= c0+160 — never read by GEMM)
    k_transpose_cvt<<<dim3(128, 128), 256, 0, stream>>>(W1, W1T, 4096, 4096, 160);
    k_transpose_cvt<<<dim3(8, 128),   256, 0, stream>>>(W2, W2T, 4096, 256, -1);
    k_transpose_cvt<<<dim3(128, 8),   256, 0, stream>>>(W0, W0T, 256, 4096, -1);

    // one-hot of shifted x
    k_onehot<<<1024, 256, 0, stream>>>(x, Xoh);

    // layer 1: A1 = elu(Xoh @ W0flat + b0)   [M=4096,N=4096,K=256, k_end=(n0+BN)>>4]
    k_gemm_bt<-4, true><<<dim3(32, 32), 256, 0, stream>>>(Xoh, W0T, b0, A1, 4096, 4096, 256);

    // layer 2: A2 = elu(A1 @ W1flat + b1)    [M=4096,N=4096,K triangular]
    k_gemm_bt<0, true><<<dim3(32, 32), 256, 0, stream>>>(A1, W1T, b1, A2, 4096, 4096, 4096);

    // layer 3: split-K partials               [M=4096,N=256]
    k_gemm_bt_splitk<4, 4><<<dim3(32, 2, 4), 256, 0, stream>>>(A2, W2T, part, 4096, 256, 4096);

    // fused reduce + bias + elu + logp
    k_logp_fused<<<1024, 256, 0, stream>>>(part, b2, x, logp);
}